// Round 5
// baseline (125.295 us; speedup 1.0000x reference)
//
#include <hip/hip_runtime.h>
#include <math.h>

#define H 4
#define HD 64
#define NN 1024
#define BB 8
#define FIN 256
#define FOUT 256

typedef _Float16 f16x8 __attribute__((ext_vector_type(8)));
typedef _Float16 f16x4 __attribute__((ext_vector_type(4)));
typedef _Float16 f16x2 __attribute__((ext_vector_type(2)));
typedef float f32x4 __attribute__((ext_vector_type(4)));

// ---------------------------------------------------------------------------
// Kernel 0: WT[f][k] = (fp16) W[k][f].  16 blocks of 64x64 tiles.
// ---------------------------------------------------------------------------
__global__ __launch_bounds__(256) void wtrans(const float* __restrict__ W,
                                              _Float16* __restrict__ WT) {
  __shared__ float tile[64][68];
  const int tid = threadIdx.x;
  const int k0 = (blockIdx.x & 3) * 64, f0 = (blockIdx.x >> 2) * 64;
  const int r = tid >> 4, c4 = (tid & 15) * 4;
#pragma unroll
  for (int p = 0; p < 4; ++p) {
    float4 v = *(const float4*)&W[(size_t)(k0 + p * 16 + r) * FOUT + f0 + c4];
    *(float4*)&tile[p * 16 + r][c4] = v;
  }
  __syncthreads();
  const int f = tid >> 2, kg = (tid & 3) * 16;
#pragma unroll
  for (int i = 0; i < 4; ++i) {
    f16x4 o;
#pragma unroll
    for (int j = 0; j < 4; ++j) o[j] = (_Float16)tile[kg + i * 4 + j][f];
    *(f16x4*)&WT[(size_t)(f0 + f) * FIN + k0 + kg + i * 4] = o;
  }
}

// ---------------------------------------------------------------------------
// Kernel 1: h = x @ W via fp16 MFMA. Block = 64 rows x 1 head, 512 blocks.
// x staged once (full K, 4096 float4s = 16/thread, coalesced); W B-frags
// read directly from WT (L2-resident, clean b128s). Epilogue fuses scores
// and stores s1, s2, u=exp(s2), v=exp(0.2*s2).
// ---------------------------------------------------------------------------
__global__ __launch_bounds__(256) void gemm_xw(const float* __restrict__ x,
                                               const _Float16* __restrict__ WT,
                                               const float* __restrict__ a,
                                               _Float16* __restrict__ hT,
                                               float* __restrict__ s1_ws,
                                               float* __restrict__ s2_ws,
                                               float* __restrict__ u_ws,
                                               float* __restrict__ v_ws) {
  __shared__ _Float16 xs[64][264];  // stride 528B: balanced for b128 reads
  const int tid = threadIdx.x;
  const int lane = tid & 63, w = tid >> 6;
  const int c = lane & 15, q = lane >> 4;
  const int bn0 = blockIdx.x * 64;
  const int head = blockIdx.y;
  const int b = bn0 >> 10, nb = bn0 & 1023;
  const int bh = b * H + head;

  // stage x tile (64 rows x 256 k), fp32->fp16.
  // 4096 float4s: iteration p covers rows p*4..p*4+3, 64 float4/row,
  // 64 threads per row -> each wave-instr reads 1KB contiguous.
#pragma unroll
  for (int p = 0; p < 16; ++p) {
    int f = p * 256 + tid;           // float4 index in [0, 4096)
    int row = f >> 6, col = (f & 63) * 4;
    float4 v = *(const float4*)&x[(size_t)(bn0 + row) * FIN + col];
    f16x4 h4;
    h4[0] = (_Float16)v.x; h4[1] = (_Float16)v.y;
    h4[2] = (_Float16)v.z; h4[3] = (_Float16)v.w;
    *(f16x4*)&xs[row][col] = h4;
  }
  __syncthreads();

  f32x4 acc[4];
#pragma unroll
  for (int t = 0; t < 4; ++t) acc[t] = (f32x4){0.f, 0.f, 0.f, 0.f};
  const _Float16* wbase = WT + (size_t)head * 64 * FIN;
#pragma unroll
  for (int ks = 0; ks < 8; ++ks) {
    f16x8 af = *(const f16x8*)&xs[w * 16 + c][ks * 32 + q * 8];
#pragma unroll
    for (int t = 0; t < 4; ++t) {
      f16x8 bf = *(const f16x8*)&wbase[(size_t)(t * 16 + c) * FIN + ks * 32 + q * 8];
      acc[t] = __builtin_amdgcn_mfma_f32_16x16x32_f16(af, bf, acc[t], 0, 0, 0);
    }
  }

  // epilogue: lane holds rows n = w*16 + q*4 + rr, cols f = t*16 + c
  float a1v[4], a2v[4];
#pragma unroll
  for (int t = 0; t < 4; ++t) {
    a1v[t] = a[head * 2 * HD + t * 16 + c];
    a2v[t] = a[head * 2 * HD + HD + t * 16 + c];
  }
  float s1p[4] = {0.f, 0.f, 0.f, 0.f};
  float s2p[4] = {0.f, 0.f, 0.f, 0.f};
#pragma unroll
  for (int t = 0; t < 4; ++t) {
    f16x4 hv;
#pragma unroll
    for (int rr = 0; rr < 4; ++rr) {
      hv[rr] = (_Float16)acc[t][rr];
      s1p[rr] += acc[t][rr] * a1v[t];
      s2p[rr] += acc[t][rr] * a2v[t];
    }
    *(f16x4*)&hT[((size_t)(bh * 64 + t * 16 + c)) * NN + nb + w * 16 + q * 4] = hv;
  }
#pragma unroll
  for (int rr = 0; rr < 4; ++rr) {
    float s1 = s1p[rr], s2 = s2p[rr];
#pragma unroll
    for (int off = 8; off; off >>= 1) {
      s1 += __shfl_xor(s1, off);
      s2 += __shfl_xor(s2, off);
    }
    if (c == 0) {
      int n = nb + w * 16 + q * 4 + rr;
      size_t idx = (size_t)bh * NN + n;
      s1_ws[idx] = s1;
      s2_ws[idx] = s2;
      u_ws[idx] = __expf(s2);
      v_ws[idx] = __expf(0.2f * s2);
    }
  }
}

// ---------------------------------------------------------------------------
// Kernel 2: attention. Block = 32 n-rows x (b,h); 1024 blocks, 4 waves.
// Rank-1 score trick: e = lrelu(s1[n]+s2[m]); row max M = lrelu(s1 + masked
// max s2); p = (s1+s2>=0) ? exp(s1-M)*u[m] : exp(.2*s1-M)*v[m]. No exp in
// the inner loops. Wave w scores rows w*8..+7 (masks in VGPRs) and owns
// output d-slice w*16..+15 for the MFMA (P fp16 via LDS, double-buffered).
// ---------------------------------------------------------------------------
__global__ __launch_bounds__(256) void attn(const _Float16* __restrict__ hT,
                                            const float* __restrict__ s1_ws,
                                            const float* __restrict__ s2_ws,
                                            const float* __restrict__ u_ws,
                                            const float* __restrict__ v_ws,
                                            const int* __restrict__ adj,
                                            float* __restrict__ out) {
  __shared__ float s2r[NN], uu[NN], vv[NN];  // 12 KB
  __shared__ _Float16 pt[2][32][136];        // 17 KB, stride 272B (balanced)
  __shared__ float invL[32];
  const int tid = threadIdx.x, lane = tid & 63, w = tid >> 6;
  const int c = lane & 15, q = lane >> 4;
  const int ntile = blockIdx.x, bh = blockIdx.y;
  const int b = bh >> 2, head = bh & 3;
  const int n0 = ntile * 32;

  {
    size_t base = (size_t)bh * NN + tid * 4;
    *(float4*)&s2r[tid * 4] = *(const float4*)&s2_ws[base];
    *(float4*)&uu[tid * 4] = *(const float4*)&u_ws[base];
    *(float4*)&vv[tid * 4] = *(const float4*)&v_ws[base];
  }
  __syncthreads();

  float s1v[8];
#pragma unroll
  for (int r = 0; r < 8; ++r) s1v[r] = s1_ws[(size_t)bh * NN + n0 + w * 8 + r];

  // ---- pass 1: masked max of s2 per row + adj bitmask (VGPR-resident) ----
  float mx[8];
  unsigned msk[8];
#pragma unroll
  for (int r = 0; r < 8; ++r) { mx[r] = -INFINITY; msk[r] = 0u; }
  const int* adjp = adj + ((size_t)(b * NN + n0 + w * 8)) * NN + 2 * lane;
#pragma unroll
  for (int ch = 0; ch < 8; ++ch) {
    int2 av[8];
#pragma unroll
    for (int r = 0; r < 8; ++r) av[r] = *(const int2*)(adjp + (size_t)r * NN + ch * 128);
    float2 s2p = *(const float2*)&s2r[ch * 128 + 2 * lane];
#pragma unroll
    for (int r = 0; r < 8; ++r) {
      bool e0 = av[r].x != 0, e1 = av[r].y != 0;
      msk[r] |= (e0 ? (1u << (2 * ch)) : 0u) | (e1 ? (2u << (2 * ch)) : 0u);
      mx[r] = fmaxf(mx[r], e0 ? s2p.x : -INFINITY);
      mx[r] = fmaxf(mx[r], e1 ? s2p.y : -INFINITY);
    }
  }
  float Arow[8], Brow[8], ns1[8];
#pragma unroll
  for (int r = 0; r < 8; ++r) {
    float m = mx[r];
#pragma unroll
    for (int off = 32; off; off >>= 1) m = fmaxf(m, __shfl_xor(m, off));
    float t0 = s1v[r] + m;
    float M = fmaxf(t0, 0.2f * t0);  // lrelu (monotone => exact row max)
    Arow[r] = __expf(s1v[r] - M);
    Brow[r] = __expf(0.2f * s1v[r] - M);
    ns1[r] = -s1v[r];
  }

  // ---- pass 2: p tiles + MFMA, double-buffered, 1 barrier/chunk ----
  float Lp[8];
#pragma unroll
  for (int r = 0; r < 8; ++r) Lp[r] = 0.f;
  f32x4 acc[2];
  acc[0] = (f32x4){0.f, 0.f, 0.f, 0.f};
  acc[1] = (f32x4){0.f, 0.f, 0.f, 0.f};
  const _Float16* bptr = hT + ((size_t)bh * 64 + w * 16 + c) * NN + q * 8;

  for (int ch = 0; ch < 8; ++ch) {
    const int buf = ch & 1;
    // B-frags for this chunk: issue early, consumed after barrier
    f16x8 bf0 = *(const f16x8*)(bptr + ch * 128);
    f16x8 bf1 = *(const f16x8*)(bptr + ch * 128 + 32);
    f16x8 bf2 = *(const f16x8*)(bptr + ch * 128 + 64);
    f16x8 bf3 = *(const f16x8*)(bptr + ch * 128 + 96);
    float2 s2p = *(const float2*)&s2r[ch * 128 + 2 * lane];
    float2 up = *(const float2*)&uu[ch * 128 + 2 * lane];
    float2 vp = *(const float2*)&vv[ch * 128 + 2 * lane];
#pragma unroll
    for (int r = 0; r < 8; ++r) {
      bool m0 = (msk[r] >> (2 * ch)) & 1u;
      bool m1 = (msk[r] >> (2 * ch + 1)) & 1u;
      float p0 = (s2p.x >= ns1[r]) ? Arow[r] * up.x : Brow[r] * vp.x;
      float p1 = (s2p.y >= ns1[r]) ? Arow[r] * up.y : Brow[r] * vp.y;
      p0 = m0 ? p0 : 0.f;
      p1 = m1 ? p1 : 0.f;
      Lp[r] += p0 + p1;
      f16x2 pk = __builtin_bit_cast(f16x2, __builtin_amdgcn_cvt_pkrtz(p0, p1));
      *(f16x2*)&pt[buf][w * 8 + r][2 * lane] = pk;
    }
    __syncthreads();
#pragma unroll
    for (int t = 0; t < 2; ++t) {
      f16x8 a0 = *(const f16x8*)&pt[buf][t * 16 + c][q * 8];
      f16x8 a1 = *(const f16x8*)&pt[buf][t * 16 + c][32 + q * 8];
      f16x8 a2 = *(const f16x8*)&pt[buf][t * 16 + c][64 + q * 8];
      f16x8 a3 = *(const f16x8*)&pt[buf][t * 16 + c][96 + q * 8];
      acc[t] = __builtin_amdgcn_mfma_f32_16x16x32_f16(a0, bf0, acc[t], 0, 0, 0);
      acc[t] = __builtin_amdgcn_mfma_f32_16x16x32_f16(a1, bf1, acc[t], 0, 0, 0);
      acc[t] = __builtin_amdgcn_mfma_f32_16x16x32_f16(a2, bf2, acc[t], 0, 0, 0);
      acc[t] = __builtin_amdgcn_mfma_f32_16x16x32_f16(a3, bf3, acc[t], 0, 0, 0);
    }
  }

  // ---- epilogue ----
  float myL = 0.f;
#pragma unroll
  for (int r = 0; r < 8; ++r) {
    float s = Lp[r];
#pragma unroll
    for (int off = 32; off; off >>= 1) s += __shfl_xor(s, off);
    if (lane == r) myL = s;
  }
  if (lane < 8) invL[w * 8 + lane] = 1.0f / myL;
  __syncthreads();
#pragma unroll
  for (int t = 0; t < 2; ++t) {
#pragma unroll
    for (int rr = 0; rr < 4; ++rr) {
      int nloc = t * 16 + q * 4 + rr;
      out[((size_t)(b * NN + n0 + nloc)) * FOUT + head * 64 + w * 16 + c] =
          acc[t][rr] * invL[nloc];
    }
  }
}

extern "C" void kernel_launch(void* const* d_in, const int* in_sizes, int n_in,
                              void* d_out, int out_size, void* d_ws, size_t ws_size,
                              hipStream_t stream) {
  const float* x = (const float*)d_in[0];
  const int* adj = (const int*)d_in[1];
  const float* W = (const float*)d_in[2];
  const float* a = (const float*)d_in[3];
  float* out = (float*)d_out;

  char* ws = (char*)d_ws;
  _Float16* hT = (_Float16*)ws;                       // 4 MB
  _Float16* WT = (_Float16*)(ws + (size_t)4 * 1024 * 1024);  // 128 KB
  float* s1_ws = (float*)(ws + (size_t)4 * 1024 * 1024 + 128 * 1024);
  float* s2_ws = s1_ws + (size_t)BB * H * NN;
  float* u_ws = s2_ws + (size_t)BB * H * NN;
  float* v_ws = u_ws + (size_t)BB * H * NN;

  wtrans<<<16, 256, 0, stream>>>(W, WT);
  gemm_xw<<<dim3(128, 4), 256, 0, stream>>>(x, WT, a, hT, s1_ws, s2_ws, u_ws, v_ws);
  attn<<<dim3(32, 32), 256, 0, stream>>>(hT, s1_ws, s2_ws, u_ws, v_ws, adj, out);
}

// Round 6
// 120.526 us; speedup vs baseline: 1.0396x; 1.0396x over previous
//
#include <hip/hip_runtime.h>
#include <math.h>

#define H 4
#define HD 64
#define NN 1024
#define BB 8
#define FIN 256
#define FOUT 256

typedef _Float16 f16x8 __attribute__((ext_vector_type(8)));
typedef _Float16 f16x4 __attribute__((ext_vector_type(4)));
typedef _Float16 f16x2 __attribute__((ext_vector_type(2)));
typedef float f32x4 __attribute__((ext_vector_type(4)));

// ---------------------------------------------------------------------------
// Kernel 0: WT[f][k] = (fp16) W[k][f].  16 blocks of 64x64 tiles.
// ---------------------------------------------------------------------------
__global__ __launch_bounds__(256) void wtrans(const float* __restrict__ W,
                                              _Float16* __restrict__ WT) {
  __shared__ float tile[64][68];
  const int tid = threadIdx.x;
  const int k0 = (blockIdx.x & 3) * 64, f0 = (blockIdx.x >> 2) * 64;
  const int r = tid >> 4, c4 = (tid & 15) * 4;
#pragma unroll
  for (int p = 0; p < 4; ++p) {
    float4 v = *(const float4*)&W[(size_t)(k0 + p * 16 + r) * FOUT + f0 + c4];
    *(float4*)&tile[p * 16 + r][c4] = v;
  }
  __syncthreads();
  const int f = tid >> 2, kg = (tid & 3) * 16;
#pragma unroll
  for (int i = 0; i < 4; ++i) {
    f16x4 o;
#pragma unroll
    for (int j = 0; j < 4; ++j) o[j] = (_Float16)tile[kg + i * 4 + j][f];
    *(f16x4*)&WT[(size_t)(f0 + f) * FIN + k0 + kg + i * 4] = o;
  }
}

// ---------------------------------------------------------------------------
// Kernel 0b: pack adj -> 1 bit/edge. adjP[(b*N+n)*32 + w] bit j = adj[b][n][w*32+j].
// Each thread: 8 int4 loads (128 B in flight) -> one uint32. Pure streaming.
// ---------------------------------------------------------------------------
__global__ __launch_bounds__(256) void adjpack(const int* __restrict__ adj,
                                               unsigned* __restrict__ adjP) {
  size_t widx = (size_t)blockIdx.x * 256 + threadIdx.x;  // [0, 8*1024*32)
  const int4* p = (const int4*)adj + widx * 8;
  int4 v[8];
#pragma unroll
  for (int i = 0; i < 8; ++i) v[i] = p[i];
  unsigned bits = 0;
#pragma unroll
  for (int i = 0; i < 8; ++i) {
    bits |= (v[i].x != 0 ? 1u : 0u) << (4 * i);
    bits |= (v[i].y != 0 ? 2u : 0u) << (4 * i);
    bits |= (v[i].z != 0 ? 4u : 0u) << (4 * i);
    bits |= (v[i].w != 0 ? 8u : 0u) << (4 * i);
  }
  adjP[widx] = bits;
}

// ---------------------------------------------------------------------------
// Kernel 1: h = x @ W via fp16 MFMA. Block = 64 rows x 1 head, 512 blocks.
// Two-phase x staging: 16 float4 loads hoisted into regs (256 B/lane in
// flight), then cvt+LDS store. W B-frags read from WT (L2-resident b128s).
// Epilogue fuses scores: s1, s2, u=exp(s2), v=exp(0.2*s2).
// ---------------------------------------------------------------------------
__global__ __launch_bounds__(256) void gemm_xw(const float* __restrict__ x,
                                               const _Float16* __restrict__ WT,
                                               const float* __restrict__ a,
                                               _Float16* __restrict__ hT,
                                               float* __restrict__ s1_ws,
                                               float* __restrict__ s2_ws,
                                               float* __restrict__ u_ws,
                                               float* __restrict__ v_ws) {
  __shared__ _Float16 xs[64][264];  // stride 528B
  const int tid = threadIdx.x;
  const int lane = tid & 63, w = tid >> 6;
  const int c = lane & 15, q = lane >> 4;
  const int bn0 = blockIdx.x * 64;
  const int head = blockIdx.y;
  const int b = bn0 >> 10, nb = bn0 & 1023;
  const int bh = b * H + head;

  // phase 1: all 16 independent loads in flight
  float4 v[16];
#pragma unroll
  for (int p = 0; p < 16; ++p) {
    int f = p * 256 + tid;  // float4 index in [0, 4096)
    int row = f >> 6, col = (f & 63) * 4;
    v[p] = *(const float4*)&x[(size_t)(bn0 + row) * FIN + col];
  }
  // phase 2: convert + store
#pragma unroll
  for (int p = 0; p < 16; ++p) {
    int f = p * 256 + tid;
    int row = f >> 6, col = (f & 63) * 4;
    f16x4 h4;
    h4[0] = (_Float16)v[p].x; h4[1] = (_Float16)v[p].y;
    h4[2] = (_Float16)v[p].z; h4[3] = (_Float16)v[p].w;
    *(f16x4*)&xs[row][col] = h4;
  }
  __syncthreads();

  f32x4 acc[4];
#pragma unroll
  for (int t = 0; t < 4; ++t) acc[t] = (f32x4){0.f, 0.f, 0.f, 0.f};
  const _Float16* wbase = WT + (size_t)head * 64 * FIN;
#pragma unroll
  for (int ks = 0; ks < 8; ++ks) {
    f16x8 af = *(const f16x8*)&xs[w * 16 + c][ks * 32 + q * 8];
#pragma unroll
    for (int t = 0; t < 4; ++t) {
      f16x8 bf = *(const f16x8*)&wbase[(size_t)(t * 16 + c) * FIN + ks * 32 + q * 8];
      acc[t] = __builtin_amdgcn_mfma_f32_16x16x32_f16(af, bf, acc[t], 0, 0, 0);
    }
  }

  // epilogue: lane holds rows n = w*16 + q*4 + rr, cols f = t*16 + c
  float a1v[4], a2v[4];
#pragma unroll
  for (int t = 0; t < 4; ++t) {
    a1v[t] = a[head * 2 * HD + t * 16 + c];
    a2v[t] = a[head * 2 * HD + HD + t * 16 + c];
  }
  float s1p[4] = {0.f, 0.f, 0.f, 0.f};
  float s2p[4] = {0.f, 0.f, 0.f, 0.f};
#pragma unroll
  for (int t = 0; t < 4; ++t) {
    f16x4 hv;
#pragma unroll
    for (int rr = 0; rr < 4; ++rr) {
      hv[rr] = (_Float16)acc[t][rr];
      s1p[rr] += acc[t][rr] * a1v[t];
      s2p[rr] += acc[t][rr] * a2v[t];
    }
    *(f16x4*)&hT[((size_t)(bh * 64 + t * 16 + c)) * NN + nb + w * 16 + q * 4] = hv;
  }
#pragma unroll
  for (int rr = 0; rr < 4; ++rr) {
    float s1 = s1p[rr], s2 = s2p[rr];
#pragma unroll
    for (int off = 8; off; off >>= 1) {
      s1 += __shfl_xor(s1, off);
      s2 += __shfl_xor(s2, off);
    }
    if (c == 0) {
      int n = nb + w * 16 + q * 4 + rr;
      size_t idx = (size_t)bh * NN + n;
      s1_ws[idx] = s1;
      s2_ws[idx] = s2;
      u_ws[idx] = __expf(s2);
      v_ws[idx] = __expf(0.2f * s2);
    }
  }
}

// ---------------------------------------------------------------------------
// Kernel 2: attention. Block = 32 n-rows x (b,h); 1024 blocks, 4 waves.
// adj mask comes from the 1-bit packed adjP: 4 KB/block staged to LDS once,
// consumed via broadcast b32 reads + bit extract -> NO HBM stream in here.
// Rank-1 score trick as before; P fp16 LDS double-buffered; MFMA for P.H.
// ---------------------------------------------------------------------------
__global__ __launch_bounds__(256) void attn(const _Float16* __restrict__ hT,
                                            const float* __restrict__ s1_ws,
                                            const float* __restrict__ s2_ws,
                                            const float* __restrict__ u_ws,
                                            const float* __restrict__ v_ws,
                                            const unsigned* __restrict__ adjP,
                                            float* __restrict__ out) {
  __shared__ float s2r[NN], uu[NN], vv[NN];  // 12 KB
  __shared__ _Float16 pt[2][32][136];        // 17 KB
  __shared__ unsigned adjW[32][32];          // 4 KB packed mask
  __shared__ float invL[32];
  const int tid = threadIdx.x, lane = tid & 63, w = tid >> 6;
  const int c = lane & 15, q = lane >> 4;
  const int ntile = blockIdx.x, bh = blockIdx.y;
  const int b = bh >> 2, head = bh & 3;
  const int n0 = ntile * 32;

  {
    size_t base = (size_t)bh * NN + tid * 4;
    *(float4*)&s2r[tid * 4] = *(const float4*)&s2_ws[base];
    *(float4*)&uu[tid * 4] = *(const float4*)&u_ws[base];
    *(float4*)&vv[tid * 4] = *(const float4*)&v_ws[base];
    uint4 aw = *(const uint4*)&adjP[((size_t)(b * NN + n0)) * 32 + tid * 4];
    *(uint4*)&adjW[tid >> 3][(tid * 4) & 31] = aw;
  }
  __syncthreads();

  float s1v[8];
#pragma unroll
  for (int r = 0; r < 8; ++r) s1v[r] = s1_ws[(size_t)bh * NN + n0 + w * 8 + r];

  const int wc = lane >> 4;           // which word within the 128-m chunk
  const int shft = (2 * lane) & 31;   // bit position of m = 2*lane

  // ---- pass 1: masked max of s2 per row (mask from LDS bits) ----
  float mx[8];
#pragma unroll
  for (int r = 0; r < 8; ++r) mx[r] = -INFINITY;
#pragma unroll
  for (int ch = 0; ch < 8; ++ch) {
    float2 s2p = *(const float2*)&s2r[ch * 128 + 2 * lane];
#pragma unroll
    for (int r = 0; r < 8; ++r) {
      unsigned bits = adjW[w * 8 + r][ch * 4 + wc] >> shft;
      mx[r] = fmaxf(mx[r], (bits & 1u) ? s2p.x : -INFINITY);
      mx[r] = fmaxf(mx[r], (bits & 2u) ? s2p.y : -INFINITY);
    }
  }
  float Arow[8], Brow[8], ns1[8];
#pragma unroll
  for (int r = 0; r < 8; ++r) {
    float m = mx[r];
#pragma unroll
    for (int off = 32; off; off >>= 1) m = fmaxf(m, __shfl_xor(m, off));
    float t0 = s1v[r] + m;
    float M = fmaxf(t0, 0.2f * t0);  // lrelu (monotone => exact row max)
    Arow[r] = __expf(s1v[r] - M);
    Brow[r] = __expf(0.2f * s1v[r] - M);
    ns1[r] = -s1v[r];
  }

  // ---- pass 2: p tiles + MFMA, double-buffered, 1 barrier/chunk ----
  float Lp[8];
#pragma unroll
  for (int r = 0; r < 8; ++r) Lp[r] = 0.f;
  f32x4 acc[2];
  acc[0] = (f32x4){0.f, 0.f, 0.f, 0.f};
  acc[1] = (f32x4){0.f, 0.f, 0.f, 0.f};
  const _Float16* bptr = hT + ((size_t)bh * 64 + w * 16 + c) * NN + q * 8;

  for (int ch = 0; ch < 8; ++ch) {
    const int buf = ch & 1;
    f16x8 bf0 = *(const f16x8*)(bptr + ch * 128);
    f16x8 bf1 = *(const f16x8*)(bptr + ch * 128 + 32);
    f16x8 bf2 = *(const f16x8*)(bptr + ch * 128 + 64);
    f16x8 bf3 = *(const f16x8*)(bptr + ch * 128 + 96);
    float2 s2p = *(const float2*)&s2r[ch * 128 + 2 * lane];
    float2 up = *(const float2*)&uu[ch * 128 + 2 * lane];
    float2 vp = *(const float2*)&vv[ch * 128 + 2 * lane];
#pragma unroll
    for (int r = 0; r < 8; ++r) {
      unsigned bits = adjW[w * 8 + r][ch * 4 + wc] >> shft;
      float p0 = (s2p.x >= ns1[r]) ? Arow[r] * up.x : Brow[r] * vp.x;
      float p1 = (s2p.y >= ns1[r]) ? Arow[r] * up.y : Brow[r] * vp.y;
      p0 = (bits & 1u) ? p0 : 0.f;
      p1 = (bits & 2u) ? p1 : 0.f;
      Lp[r] += p0 + p1;
      f16x2 pk = __builtin_bit_cast(f16x2, __builtin_amdgcn_cvt_pkrtz(p0, p1));
      *(f16x2*)&pt[buf][w * 8 + r][2 * lane] = pk;
    }
    __syncthreads();
#pragma unroll
    for (int t = 0; t < 2; ++t) {
      f16x8 a0 = *(const f16x8*)&pt[buf][t * 16 + c][q * 8];
      f16x8 a1 = *(const f16x8*)&pt[buf][t * 16 + c][32 + q * 8];
      f16x8 a2 = *(const f16x8*)&pt[buf][t * 16 + c][64 + q * 8];
      f16x8 a3 = *(const f16x8*)&pt[buf][t * 16 + c][96 + q * 8];
      acc[t] = __builtin_amdgcn_mfma_f32_16x16x32_f16(a0, bf0, acc[t], 0, 0, 0);
      acc[t] = __builtin_amdgcn_mfma_f32_16x16x32_f16(a1, bf1, acc[t], 0, 0, 0);
      acc[t] = __builtin_amdgcn_mfma_f32_16x16x32_f16(a2, bf2, acc[t], 0, 0, 0);
      acc[t] = __builtin_amdgcn_mfma_f32_16x16x32_f16(a3, bf3, acc[t], 0, 0, 0);
    }
  }

  // ---- epilogue ----
  float myL = 0.f;
#pragma unroll
  for (int r = 0; r < 8; ++r) {
    float s = Lp[r];
#pragma unroll
    for (int off = 32; off; off >>= 1) s += __shfl_xor(s, off);
    if (lane == r) myL = s;
  }
  if (lane < 8) invL[w * 8 + lane] = 1.0f / myL;
  __syncthreads();
#pragma unroll
  for (int t = 0; t < 2; ++t) {
#pragma unroll
    for (int rr = 0; rr < 4; ++rr) {
      int nloc = t * 16 + q * 4 + rr;
      out[((size_t)(b * NN + n0 + nloc)) * FOUT + head * 64 + w * 16 + c] =
          acc[t][rr] * invL[nloc];
    }
  }
}

extern "C" void kernel_launch(void* const* d_in, const int* in_sizes, int n_in,
                              void* d_out, int out_size, void* d_ws, size_t ws_size,
                              hipStream_t stream) {
  const float* x = (const float*)d_in[0];
  const int* adj = (const int*)d_in[1];
  const float* W = (const float*)d_in[2];
  const float* a = (const float*)d_in[3];
  float* out = (float*)d_out;

  char* ws = (char*)d_ws;
  _Float16* hT = (_Float16*)ws;                              // 4 MB
  _Float16* WT = (_Float16*)(ws + (size_t)4 * 1024 * 1024);  // 128 KB
  float* s1_ws = (float*)(ws + (size_t)4 * 1024 * 1024 + 128 * 1024);
  float* s2_ws = s1_ws + (size_t)BB * H * NN;
  float* u_ws = s2_ws + (size_t)BB * H * NN;
  float* v_ws = u_ws + (size_t)BB * H * NN;
  unsigned* adjP = (unsigned*)(v_ws + (size_t)BB * H * NN);  // 1 MB

  wtrans<<<16, 256, 0, stream>>>(W, WT);
  adjpack<<<1024, 256, 0, stream>>>(adj, adjP);
  gemm_xw<<<dim3(128, 4), 256, 0, stream>>>(x, WT, a, hT, s1_ws, s2_ws, u_ws, v_ws);
  attn<<<dim3(32, 32), 256, 0, stream>>>(hT, s1_ws, s2_ws, u_ws, v_ws, adjP, out);
}

// Round 7
// 119.142 us; speedup vs baseline: 1.0516x; 1.0116x over previous
//
#include <hip/hip_runtime.h>
#include <math.h>

#define H 4
#define HD 64
#define NN 1024
#define BB 8
#define FIN 256
#define FOUT 256

typedef _Float16 f16x8 __attribute__((ext_vector_type(8)));
typedef _Float16 f16x4 __attribute__((ext_vector_type(4)));
typedef _Float16 f16x2 __attribute__((ext_vector_type(2)));
typedef float f32x4 __attribute__((ext_vector_type(4)));

// ---------------------------------------------------------------------------
// Kernel 0: prep. Blocks 0..1023: pack adj -> 1 bit/edge (streaming).
// Blocks 1024..1039: WT[f][k] = (fp16) W[k][f] in 64x64 tiles.
// ---------------------------------------------------------------------------
__global__ __launch_bounds__(256) void prep(const int* __restrict__ adj,
                                            unsigned* __restrict__ adjP,
                                            const float* __restrict__ W,
                                            _Float16* __restrict__ WT) {
  __shared__ float tile[64][68];
  const int tid = threadIdx.x;
  if (blockIdx.x < 1024) {
    size_t widx = (size_t)blockIdx.x * 256 + tid;  // [0, 8*1024*32)
    const int4* p = (const int4*)adj + widx * 8;
    int4 v[8];
#pragma unroll
    for (int i = 0; i < 8; ++i) v[i] = p[i];
    unsigned bits = 0;
#pragma unroll
    for (int i = 0; i < 8; ++i) {
      bits |= (v[i].x != 0 ? 1u : 0u) << (4 * i);
      bits |= (v[i].y != 0 ? 2u : 0u) << (4 * i);
      bits |= (v[i].z != 0 ? 4u : 0u) << (4 * i);
      bits |= (v[i].w != 0 ? 8u : 0u) << (4 * i);
    }
    adjP[widx] = bits;
  } else {
    const int bx = blockIdx.x - 1024;
    const int k0 = (bx & 3) * 64, f0 = (bx >> 2) * 64;
    const int r = tid >> 4, c4 = (tid & 15) * 4;
#pragma unroll
    for (int p = 0; p < 4; ++p) {
      float4 v = *(const float4*)&W[(size_t)(k0 + p * 16 + r) * FOUT + f0 + c4];
      *(float4*)&tile[p * 16 + r][c4] = v;
    }
    __syncthreads();
    const int f = tid >> 2, kg = (tid & 3) * 16;
#pragma unroll
    for (int i = 0; i < 4; ++i) {
      f16x4 o;
#pragma unroll
      for (int j = 0; j < 4; ++j) o[j] = (_Float16)tile[kg + i * 4 + j][f];
      *(f16x4*)&WT[(size_t)(f0 + f) * FIN + k0 + kg + i * 4] = o;
    }
  }
}

// ---------------------------------------------------------------------------
// Kernel 1: h = x @ W via fp16 MFMA. Block = 64 rows x 1 head, 512 blocks.
// Two-phase x staging (16 float4 in flight); W B-frags from WT (L2 b128s).
// Epilogue fuses scores: s1, s2, u=exp(s2), v=exp(0.2*s2).
// ---------------------------------------------------------------------------
__global__ __launch_bounds__(256) void gemm_xw(const float* __restrict__ x,
                                               const _Float16* __restrict__ WT,
                                               const float* __restrict__ a,
                                               _Float16* __restrict__ hT,
                                               float* __restrict__ s1_ws,
                                               float* __restrict__ s2_ws,
                                               float* __restrict__ u_ws,
                                               float* __restrict__ v_ws) {
  __shared__ _Float16 xs[64][264];  // stride 528B
  const int tid = threadIdx.x;
  const int lane = tid & 63, w = tid >> 6;
  const int c = lane & 15, q = lane >> 4;
  const int bn0 = blockIdx.x * 64;
  const int head = blockIdx.y;
  const int b = bn0 >> 10, nb = bn0 & 1023;
  const int bh = b * H + head;

  float4 v[16];
#pragma unroll
  for (int p = 0; p < 16; ++p) {
    int f = p * 256 + tid;  // float4 index in [0, 4096)
    int row = f >> 6, col = (f & 63) * 4;
    v[p] = *(const float4*)&x[(size_t)(bn0 + row) * FIN + col];
  }
#pragma unroll
  for (int p = 0; p < 16; ++p) {
    int f = p * 256 + tid;
    int row = f >> 6, col = (f & 63) * 4;
    f16x4 h4;
    h4[0] = (_Float16)v[p].x; h4[1] = (_Float16)v[p].y;
    h4[2] = (_Float16)v[p].z; h4[3] = (_Float16)v[p].w;
    *(f16x4*)&xs[row][col] = h4;
  }
  __syncthreads();

  f32x4 acc[4];
#pragma unroll
  for (int t = 0; t < 4; ++t) acc[t] = (f32x4){0.f, 0.f, 0.f, 0.f};
  const _Float16* wbase = WT + (size_t)head * 64 * FIN;
#pragma unroll
  for (int ks = 0; ks < 8; ++ks) {
    f16x8 af = *(const f16x8*)&xs[w * 16 + c][ks * 32 + q * 8];
#pragma unroll
    for (int t = 0; t < 4; ++t) {
      f16x8 bf = *(const f16x8*)&wbase[(size_t)(t * 16 + c) * FIN + ks * 32 + q * 8];
      acc[t] = __builtin_amdgcn_mfma_f32_16x16x32_f16(af, bf, acc[t], 0, 0, 0);
    }
  }

  float a1v[4], a2v[4];
#pragma unroll
  for (int t = 0; t < 4; ++t) {
    a1v[t] = a[head * 2 * HD + t * 16 + c];
    a2v[t] = a[head * 2 * HD + HD + t * 16 + c];
  }
  float s1p[4] = {0.f, 0.f, 0.f, 0.f};
  float s2p[4] = {0.f, 0.f, 0.f, 0.f};
#pragma unroll
  for (int t = 0; t < 4; ++t) {
    f16x4 hv;
#pragma unroll
    for (int rr = 0; rr < 4; ++rr) {
      hv[rr] = (_Float16)acc[t][rr];
      s1p[rr] += acc[t][rr] * a1v[t];
      s2p[rr] += acc[t][rr] * a2v[t];
    }
    *(f16x4*)&hT[((size_t)(bh * 64 + t * 16 + c)) * NN + nb + w * 16 + q * 4] = hv;
  }
#pragma unroll
  for (int rr = 0; rr < 4; ++rr) {
    float s1 = s1p[rr], s2 = s2p[rr];
#pragma unroll
    for (int off = 8; off; off >>= 1) {
      s1 += __shfl_xor(s1, off);
      s2 += __shfl_xor(s2, off);
    }
    if (c == 0) {
      int n = nb + w * 16 + q * 4 + rr;
      size_t idx = (size_t)bh * NN + n;
      s1_ws[idx] = s1;
      s2_ws[idx] = s2;
      u_ws[idx] = __expf(s2);
      v_ws[idx] = __expf(0.2f * s2);
    }
  }
}

// ---------------------------------------------------------------------------
// Kernel 2: attention. Block = 32 n-rows x (b,h); 1024 blocks, 4 waves.
// Packed adj from LDS (no HBM stream). Rank-1 score factorization.
// Software-pipelined: bf (hT B-frags) for chunk ch+1 are issued before the
// barrier of chunk ch, so L2/L3 latency is hidden by a full chunk of work.
// ---------------------------------------------------------------------------
__global__ __launch_bounds__(256) void attn(const _Float16* __restrict__ hT,
                                            const float* __restrict__ s1_ws,
                                            const float* __restrict__ s2_ws,
                                            const float* __restrict__ u_ws,
                                            const float* __restrict__ v_ws,
                                            const unsigned* __restrict__ adjP,
                                            float* __restrict__ out) {
  __shared__ float s2r[NN], uu[NN], vv[NN];  // 12 KB
  __shared__ _Float16 pt[2][32][136];        // 17 KB
  __shared__ unsigned adjW[32][32];          // 4 KB packed mask
  __shared__ float invL[32];
  const int tid = threadIdx.x, lane = tid & 63, w = tid >> 6;
  const int c = lane & 15, q = lane >> 4;
  const int ntile = blockIdx.x, bh = blockIdx.y;
  const int b = bh >> 2, head = bh & 3;
  const int n0 = ntile * 32;

  {
    size_t base = (size_t)bh * NN + tid * 4;
    *(float4*)&s2r[tid * 4] = *(const float4*)&s2_ws[base];
    *(float4*)&uu[tid * 4] = *(const float4*)&u_ws[base];
    *(float4*)&vv[tid * 4] = *(const float4*)&v_ws[base];
    uint4 aw = *(const uint4*)&adjP[((size_t)(b * NN + n0)) * 32 + tid * 4];
    *(uint4*)&adjW[tid >> 3][(tid * 4) & 31] = aw;
  }
  __syncthreads();

  float s1v[8];
#pragma unroll
  for (int r = 0; r < 8; ++r) s1v[r] = s1_ws[(size_t)bh * NN + n0 + w * 8 + r];

  const int wc = lane >> 4;          // word within the 128-m chunk
  const int shft = (2 * lane) & 31;  // bit position of m = 2*lane

  // ---- pass 1: masked max of s2 per row (mask bits from LDS) ----
  float mx[8];
#pragma unroll
  for (int r = 0; r < 8; ++r) mx[r] = -INFINITY;
#pragma unroll
  for (int ch = 0; ch < 8; ++ch) {
    float2 s2p = *(const float2*)&s2r[ch * 128 + 2 * lane];
#pragma unroll
    for (int r = 0; r < 8; ++r) {
      unsigned bits = adjW[w * 8 + r][ch * 4 + wc] >> shft;
      mx[r] = fmaxf(mx[r], (bits & 1u) ? s2p.x : -INFINITY);
      mx[r] = fmaxf(mx[r], (bits & 2u) ? s2p.y : -INFINITY);
    }
  }
  float Arow[8], Brow[8], ns1[8];
#pragma unroll
  for (int r = 0; r < 8; ++r) {
    float m = mx[r];
#pragma unroll
    for (int off = 32; off; off >>= 1) m = fmaxf(m, __shfl_xor(m, off));
    float t0 = s1v[r] + m;
    float M = fmaxf(t0, 0.2f * t0);  // lrelu (monotone => exact row max)
    Arow[r] = __expf(s1v[r] - M);
    Brow[r] = __expf(0.2f * s1v[r] - M);
    ns1[r] = -s1v[r];
  }

  // ---- pass 2: software-pipelined p tiles + MFMA ----
  float Lp[8];
#pragma unroll
  for (int r = 0; r < 8; ++r) Lp[r] = 0.f;
  f32x4 acc[2];
  acc[0] = (f32x4){0.f, 0.f, 0.f, 0.f};
  acc[1] = (f32x4){0.f, 0.f, 0.f, 0.f};
  const _Float16* bptr = hT + ((size_t)bh * 64 + w * 16 + c) * NN + q * 8;

  // prefetch chunk 0 B-frags
  f16x8 nbf0 = *(const f16x8*)(bptr);
  f16x8 nbf1 = *(const f16x8*)(bptr + 32);
  f16x8 nbf2 = *(const f16x8*)(bptr + 64);
  f16x8 nbf3 = *(const f16x8*)(bptr + 96);

  for (int ch = 0; ch < 8; ++ch) {
    const int buf = ch & 1;
    f16x8 bf0 = nbf0, bf1 = nbf1, bf2 = nbf2, bf3 = nbf3;
    float2 s2p = *(const float2*)&s2r[ch * 128 + 2 * lane];
    float2 up = *(const float2*)&uu[ch * 128 + 2 * lane];
    float2 vp = *(const float2*)&vv[ch * 128 + 2 * lane];
#pragma unroll
    for (int r = 0; r < 8; ++r) {
      unsigned bits = adjW[w * 8 + r][ch * 4 + wc] >> shft;
      float p0 = (s2p.x >= ns1[r]) ? Arow[r] * up.x : Brow[r] * vp.x;
      float p1 = (s2p.y >= ns1[r]) ? Arow[r] * up.y : Brow[r] * vp.y;
      p0 = (bits & 1u) ? p0 : 0.f;
      p1 = (bits & 2u) ? p1 : 0.f;
      Lp[r] += p0 + p1;
      f16x2 pk = __builtin_bit_cast(f16x2, __builtin_amdgcn_cvt_pkrtz(p0, p1));
      *(f16x2*)&pt[buf][w * 8 + r][2 * lane] = pk;
    }
    if (ch < 7) {  // issue next chunk's B-frags; consumed after NEXT barrier
      nbf0 = *(const f16x8*)(bptr + (ch + 1) * 128);
      nbf1 = *(const f16x8*)(bptr + (ch + 1) * 128 + 32);
      nbf2 = *(const f16x8*)(bptr + (ch + 1) * 128 + 64);
      nbf3 = *(const f16x8*)(bptr + (ch + 1) * 128 + 96);
    }
    __syncthreads();
#pragma unroll
    for (int t = 0; t < 2; ++t) {
      f16x8 a0 = *(const f16x8*)&pt[buf][t * 16 + c][q * 8];
      f16x8 a1 = *(const f16x8*)&pt[buf][t * 16 + c][32 + q * 8];
      f16x8 a2 = *(const f16x8*)&pt[buf][t * 16 + c][64 + q * 8];
      f16x8 a3 = *(const f16x8*)&pt[buf][t * 16 + c][96 + q * 8];
      acc[t] = __builtin_amdgcn_mfma_f32_16x16x32_f16(a0, bf0, acc[t], 0, 0, 0);
      acc[t] = __builtin_amdgcn_mfma_f32_16x16x32_f16(a1, bf1, acc[t], 0, 0, 0);
      acc[t] = __builtin_amdgcn_mfma_f32_16x16x32_f16(a2, bf2, acc[t], 0, 0, 0);
      acc[t] = __builtin_amdgcn_mfma_f32_16x16x32_f16(a3, bf3, acc[t], 0, 0, 0);
    }
  }

  // ---- epilogue ----
  float myL = 0.f;
#pragma unroll
  for (int r = 0; r < 8; ++r) {
    float s = Lp[r];
#pragma unroll
    for (int off = 32; off; off >>= 1) s += __shfl_xor(s, off);
    if (lane == r) myL = s;
  }
  if (lane < 8) invL[w * 8 + lane] = 1.0f / myL;
  __syncthreads();
#pragma unroll
  for (int t = 0; t < 2; ++t) {
#pragma unroll
    for (int rr = 0; rr < 4; ++rr) {
      int nloc = t * 16 + q * 4 + rr;
      out[((size_t)(b * NN + n0 + nloc)) * FOUT + head * 64 + w * 16 + c] =
          acc[t][rr] * invL[nloc];
    }
  }
}

extern "C" void kernel_launch(void* const* d_in, const int* in_sizes, int n_in,
                              void* d_out, int out_size, void* d_ws, size_t ws_size,
                              hipStream_t stream) {
  const float* x = (const float*)d_in[0];
  const int* adj = (const int*)d_in[1];
  const float* W = (const float*)d_in[2];
  const float* a = (const float*)d_in[3];
  float* out = (float*)d_out;

  char* ws = (char*)d_ws;
  _Float16* hT = (_Float16*)ws;                              // 4 MB
  _Float16* WT = (_Float16*)(ws + (size_t)4 * 1024 * 1024);  // 128 KB
  float* s1_ws = (float*)(ws + (size_t)4 * 1024 * 1024 + 128 * 1024);
  float* s2_ws = s1_ws + (size_t)BB * H * NN;
  float* u_ws = s2_ws + (size_t)BB * H * NN;
  float* v_ws = u_ws + (size_t)BB * H * NN;
  unsigned* adjP = (unsigned*)(v_ws + (size_t)BB * H * NN);  // 1 MB

  prep<<<1040, 256, 0, stream>>>(adj, adjP, W, WT);
  gemm_xw<<<dim3(128, 4), 256, 0, stream>>>(x, WT, a, hT, s1_ws, s2_ws, u_ws, v_ws);
  attn<<<dim3(32, 32), 256, 0, stream>>>(hT, s1_ws, s2_ws, u_ws, v_ws, adjP, out);
}